// Round 5
// baseline (752.259 us; speedup 1.0000x reference)
//
#include <hip/hip_runtime.h>
#include <math.h>

typedef unsigned short u16;
typedef unsigned int u32;
typedef __bf16 bf16x8 __attribute__((ext_vector_type(8)));
typedef float f32x4 __attribute__((ext_vector_type(4)));

__device__ __forceinline__ float b2f(u16 u) { return __uint_as_float(((u32)u) << 16); }
__device__ __forceinline__ u16 f2b(float f) {
    u32 x = __float_as_uint(f);
    return (u16)((x + 0x7FFFu + ((x >> 16) & 1u)) >> 16);
}
__device__ __forceinline__ void load8f(const float* p, size_t idx, float* o) {
    const float4* q = (const float4*)(p + idx);
    float4 a = q[0], b = q[1];
    o[0]=a.x; o[1]=a.y; o[2]=a.z; o[3]=a.w; o[4]=b.x; o[5]=b.y; o[6]=b.z; o[7]=b.w;
}
// async global->LDS, 16B per lane; LDS dest = wave-uniform base + lane*16
__device__ __forceinline__ void gld16(const void* g, void* l) {
    __builtin_amdgcn_global_load_lds(
        (const __attribute__((address_space(1))) u32*)g,
        (__attribute__((address_space(3))) u32*)l, 16, 0, 0);
}

// ---------------- weight transpose+convert: Wt[n][k] = bf16(W[k][n] * scale) ----------------
__global__ __launch_bounds__(256) void transpose_k(const float* __restrict__ Win, u16* __restrict__ Wt,
                                                   int Kd, int Nd, float scale) {
    __shared__ u16 tile[32][33];
    int tx = threadIdx.x & 31, ty = threadIdx.x >> 5;
    int k0 = blockIdx.x << 5, n0 = blockIdx.y << 5;
#pragma unroll
    for (int r = 0; r < 4; r++)
        tile[ty + 8 * r][tx] = f2b(Win[(size_t)(k0 + ty + 8 * r) * Nd + (n0 + tx)] * scale);
    __syncthreads();
#pragma unroll
    for (int r = 0; r < 4; r++)
        Wt[(size_t)(n0 + ty + 8 * r) * Kd + (k0 + tx)] = tile[tx][ty + 8 * r];
}

// ---------------- concat qkv bias (scale folded into q part) ----------------
__global__ __launch_bounds__(256) void biascat_k(const float* __restrict__ bq, const float* __restrict__ bk,
                                                 const float* __restrict__ bv, float* __restrict__ o) {
    int i = blockIdx.x * 256 + threadIdx.x;   // 1536
    float v = (i < 512) ? bq[i] * 0.17677669529663689f : (i < 1024 ? bk[i - 512] : bv[i - 1024]);
    o[i] = v;
}

// ---------------- LN1 (stats fused) + shift + window partition ----------------
__global__ __launch_bounds__(256) void ln1win_k(const float* __restrict__ x, const float* __restrict__ g,
                                                const float* __restrict__ bta, u16* __restrict__ win) {
    int wave = threadIdx.x >> 6, lane = threadIdx.x & 63;
    int token = blockIdx.x * 4 + wave;                  // token-order row
    int b = token / 4800, rem = token - b * 4800;
    int h = rem / 60, w = rem - h * 60;
    int hr = h + 75; if (hr >= 80) hr -= 80;            // (h-5) mod 80 : rolled coord
    int wr = w + 55; if (wr >= 60) wr -= 60;
    int widx = (hr / 10) * 6 + (wr / 10);
    int l = (hr - (hr / 10) * 10) * 10 + (wr - (wr / 10) * 10);
    size_t dstrow = ((size_t)b * 48 + widx) * 100 + l;  // window-order row
    int c0 = lane * 8;
    float v[8]; load8f(x, (size_t)token * 512 + c0, v);
    float s = 0.f, s2 = 0.f;
#pragma unroll
    for (int e = 0; e < 8; e++) { s += v[e]; s2 += v[e] * v[e]; }
#pragma unroll
    for (int o = 32; o > 0; o >>= 1) { s += __shfl_xor(s, o); s2 += __shfl_xor(s2, o); }
    float mean = s * (1.0f / 512.0f);
    float var = fmaxf(s2 * (1.0f / 512.0f) - mean * mean, 0.0f);
    float rstd = rsqrtf(var + 1e-5f);
    uint4 o4; u16* ou = (u16*)&o4;
#pragma unroll
    for (int e = 0; e < 8; e++)
        ou[e] = f2b((v[e] - mean) * rstd * g[c0 + e] + bta[c0 + e]);
    *(uint4*)(win + dstrow * 512 + c0) = o4;
}

// ---------------- window reverse + residual + fused LN2: hs, ln2y ----------------
__global__ __launch_bounds__(256) void resid2_k(const float* __restrict__ shortcut, const u16* __restrict__ attn_out,
                                                const float* __restrict__ g, const float* __restrict__ bta,
                                                u16* __restrict__ hs, u16* __restrict__ ln2y) {
    int wave = threadIdx.x >> 6, lane = threadIdx.x & 63;
    int token = blockIdx.x * 4 + wave;
    int b = token / 4800, rem = token - b * 4800;
    int h = rem / 60, w = rem - h * 60;
    int hr = h + 75; if (hr >= 80) hr -= 80;
    int wr = w + 55; if (wr >= 60) wr -= 60;
    int widx = (hr / 10) * 6 + (wr / 10);
    int l = (hr - (hr / 10) * 10) * 10 + (wr - (wr / 10) * 10);
    size_t arow = ((size_t)b * 48 + widx) * 100 + l;
    int c0 = lane * 8;
    float sv[8]; load8f(shortcut, (size_t)token * 512 + c0, sv);
    uint4 da = *(const uint4*)(attn_out + arow * 512 + c0);
    const u16* au = (const u16*)&da;
    float hv[8]; float s = 0.f, s2 = 0.f;
    uint4 oh; u16* ohu = (u16*)&oh;
#pragma unroll
    for (int e = 0; e < 8; e++) {
        hv[e] = sv[e] + b2f(au[e]);
        s += hv[e]; s2 += hv[e] * hv[e];
        ohu[e] = f2b(hv[e]);
    }
    *(uint4*)(hs + (size_t)token * 512 + c0) = oh;
#pragma unroll
    for (int off = 32; off > 0; off >>= 1) { s += __shfl_xor(s, off); s2 += __shfl_xor(s2, off); }
    float mean = s * (1.0f / 512.0f);
    float var = fmaxf(s2 * (1.0f / 512.0f) - mean * mean, 0.0f);
    float rstd = rsqrtf(var + 1e-5f);
    uint4 oy; u16* oyu = (u16*)&oy;
#pragma unroll
    for (int e = 0; e < 8; e++)
        oyu[e] = f2b((hv[e] - mean) * rstd * g[c0 + e] + bta[c0 + e]);
    *(uint4*)(ln2y + (size_t)token * 512 + c0) = oy;
}

// ---------------- 256x256 MFMA GEMM, 4-phase counted-vmcnt schedule (T2+T3+T4+T5) ----------------
// C[M,Nstride] = epi(A[M,K] @ Bt[Ntot,K]^T + bias). 512 threads = 8 waves (2M x 4N), BK=64.
// LDS: 2 buffers x (A 256x64 + B 256x64) bf16 = 128KB. Per wave output 128x64 (acc[8][4]).
// T2 swizzle (rule #21 both-sides): LDS dest linear (gld16); 16B-chunk permutation chunk^=(row&7)
//   applied on the GLOBAL source address per lane AND on the ds_read address. Verified mapping:
//   LDS[row][c] holds global chunk c^(row&7); read chunk (ks*4+quad)^(row&7) yields k=ks*32+quad*8.
// T4 vmcnt ledger (per wave, 2 loads/phase, issue order B01,B23,A02,A13 of tile t+1 during tile t):
//   P0 needs tile-t B0-3+A0,A2 -> vmcnt(4) (leaves A1A3(t)+B01(t+1));
//   P1 needs A1,A3 -> vmcnt(4) (leaves B01,B23 of t+1). Never drains below 4 mid-loop.
// Barriers: P0,P1 (after vmcnt, before reads); P3 (after lgkmcnt(0), before MFMA — protects buf
//   cur from next tile's stage writes). Phases P2,P3 stage A-halves (needed 2+ phases later).
// EPI: 0 = bias; 1 = bias+tanh-GELU; 2 = bias+residual (res bf16 [M,512]). OF32: fp32 out.
// QKV: Nstride=512; bn covers 1536 cols in 256-tiles; route by bn>>1; bias indexed 0..1535.
template <int EPI, int OF32, int QKV>
__global__ __launch_bounds__(512, 2) void gemm_k(const u16* __restrict__ A, const u16* __restrict__ Bt,
                                                 const float* __restrict__ bias, const u16* __restrict__ res,
                                                 void* __restrict__ C0, void* __restrict__ C1, void* __restrict__ C2,
                                                 int M, int N, int K) {
    __shared__ __align__(16) u16 As[2][256 * 64];
    __shared__ __align__(16) u16 Bs[2][256 * 64];
    int tid = threadIdx.x;
    int wave = tid >> 6, lane = tid & 63;
    int l15 = lane & 15, quad = lane >> 4;
    int wr = wave >> 2, wc = wave & 3;            // 2 x 4 wave grid

    // XCD-aware chunked bijective swizzle from the true hw dispatch id (x-fastest).
    int gy = gridDim.y;
    int nwg = gridDim.x * gy;
    int lid = blockIdx.x + blockIdx.y * gridDim.x;
    int xcd = lid & 7, loc = lid >> 3;
    int q8 = nwg >> 3, r8 = nwg & 7;
    int wg = (xcd < r8 ? xcd * (q8 + 1) : r8 * (q8 + 1) + (xcd - r8) * q8) + loc;
    int bn = wg % gy, bm = wg / gy;

    f32x4 acc[8][4];
#pragma unroll
    for (int i = 0; i < 8; i++)
#pragma unroll
        for (int j = 0; j < 4; j++) acc[i][j] = (f32x4){0.f, 0.f, 0.f, 0.f};

    const u16* Ab = A + (size_t)(bm * 256) * K;
    const u16* Bb = Bt + (size_t)(bn * 256) * K;

    // staging lane constants: lane covers row wbase+(lane>>3), source chunk (lane&7)^(lane>>3 &7)
    int lrow = lane >> 3;
    int cg = (lane & 7) ^ lrow;
    size_t gOff = (size_t)(wave * 8 + lrow) * K + cg * 8;
    // read lane constants
    int e = l15 & 7;
    int xk0 = (quad ^ e) * 8;       // u16 offset of swizzled chunk, ks=0
    int xk1 = xk0 ^ 32;             // ks=1  ((4+quad)^e)*8
    int aRow = (wr * 128 + l15) * 64;
    int bRow = (wc * 64 + l15) * 64;

    auto STAGE_A = [&](int b, int kt, int i) {
        gld16(Ab + (size_t)(i * 64) * K + kt + gOff, &As[b][(i * 64 + wave * 8) * 64]);
    };
    auto STAGE_B = [&](int b, int kt, int j) {
        gld16(Bb + (size_t)(j * 64) * K + kt + gOff, &Bs[b][(j * 64 + wave * 8) * 64]);
    };

#define MM16(MH)                                                                     \
    do {                                                                             \
        __builtin_amdgcn_s_setprio(1);                                               \
        _Pragma("unroll") for (int i_ = 0; i_ < 4; i_++)                             \
            _Pragma("unroll") for (int n_ = 0; n_ < 4; n_++)                         \
                acc[(MH) * 4 + i_][n_] = __builtin_amdgcn_mfma_f32_16x16x32_bf16(    \
                    a_[i_], b_[n_], acc[(MH) * 4 + i_][n_], 0, 0, 0);                \
        __builtin_amdgcn_s_setprio(0);                                               \
    } while (0)

    int T = K >> 6;   // K-tiles of 64; K in {512, 2048}
    // prologue: tile 0 into buf 0, ledger order
    STAGE_B(0, 0, 0); STAGE_B(0, 0, 1);
    STAGE_B(0, 0, 2); STAGE_B(0, 0, 3);
    STAGE_A(0, 0, 0); STAGE_A(0, 0, 2);
    STAGE_A(0, 0, 1); STAGE_A(0, 0, 3);

#pragma unroll 1
    for (int t = 0; t < T; t++) {
        int cur = t & 1, nxt = cur ^ 1;
        int ktn = (t + 1) << 6;
        bool pf = (t + 1 < T);
        bf16x8 a_[4], b_[4];
        // ---------- P0: stage B01(t+1) | wait tile-t B+A02 | MFMA mh0 ks0 ----------
        if (pf) {
            STAGE_B(nxt, ktn, 0); STAGE_B(nxt, ktn, 1);
            asm volatile("s_waitcnt vmcnt(4)" ::: "memory");
        } else {
            asm volatile("s_waitcnt vmcnt(2)" ::: "memory");
        }
        __builtin_amdgcn_s_barrier();
        asm volatile("" ::: "memory");
#pragma unroll
        for (int n = 0; n < 4; n++) b_[n] = *(const bf16x8*)(&Bs[cur][bRow + n * 1024 + xk0]);
#pragma unroll
        for (int i = 0; i < 4; i++) a_[i] = *(const bf16x8*)(&As[cur][aRow + i * 1024 + xk0]);
        MM16(0);
        // ---------- P1: stage B23(t+1) | wait A13(t) | MFMA mh1 ks0 ----------
        if (pf) {
            STAGE_B(nxt, ktn, 2); STAGE_B(nxt, ktn, 3);
            asm volatile("s_waitcnt vmcnt(4)" ::: "memory");
        } else {
            asm volatile("s_waitcnt vmcnt(0)" ::: "memory");
        }
        __builtin_amdgcn_s_barrier();
        asm volatile("" ::: "memory");
#pragma unroll
        for (int i = 0; i < 4; i++) a_[i] = *(const bf16x8*)(&As[cur][aRow + (4 + i) * 1024 + xk0]);
        MM16(1);
        // ---------- P2: stage A0,A2(t+1) | MFMA mh0 ks1 (tile resident, no sync) ----------
        if (pf) { STAGE_A(nxt, ktn, 0); STAGE_A(nxt, ktn, 2); }
#pragma unroll
        for (int n = 0; n < 4; n++) b_[n] = *(const bf16x8*)(&Bs[cur][bRow + n * 1024 + xk1]);
#pragma unroll
        for (int i = 0; i < 4; i++) a_[i] = *(const bf16x8*)(&As[cur][aRow + i * 1024 + xk1]);
        MM16(0);
        // ---------- P3: stage A1,A3(t+1) | reads, then barrier protecting buf cur ----------
        if (pf) { STAGE_A(nxt, ktn, 1); STAGE_A(nxt, ktn, 3); }
#pragma unroll
        for (int i = 0; i < 4; i++) a_[i] = *(const bf16x8*)(&As[cur][aRow + (4 + i) * 1024 + xk1]);
        asm volatile("s_waitcnt lgkmcnt(0)" ::: "memory");
        __builtin_amdgcn_sched_barrier(0);
        __builtin_amdgcn_s_barrier();   // all waves' reads of buf cur in regs; next tile may stage into it
        asm volatile("" ::: "memory");
        MM16(1);
    }
#undef MM16

    // epilogue. C/D frag layout: col = l15, row = quad*4 + rr
    u16* Cd = (u16*)C0;
    if (QKV) {
        int sel = bn >> 1;
        Cd = (sel == 0) ? (u16*)C0 : (sel == 1) ? (u16*)C1 : (u16*)C2;
    }
#pragma unroll
    for (int m = 0; m < 8; m++) {
        int row0 = bm * 256 + wr * 128 + m * 16 + quad * 4;
#pragma unroll
        for (int n = 0; n < 4; n++) {
            int colg = bn * 256 + wc * 64 + n * 16 + l15;
            int col = QKV ? (colg & 511) : colg;
            float bv = bias[colg];
#pragma unroll
            for (int rr = 0; rr < 4; rr++) {
                int row = row0 + rr;
                float v = acc[m][n][rr] + bv;
                if (EPI == 1) {   // tanh-form GELU
                    float zz = 1.5957691216f * (v + 0.044715f * v * v * v);
                    float tt = 1.0f - 2.0f / (__expf(zz) + 1.0f);
                    v = 0.5f * v * (1.0f + tt);
                }
                if (EPI == 2) v += b2f(res[(size_t)row * 512 + col]);
                if (OF32) ((float*)Cd)[(size_t)row * N + col] = v;
                else      ((u16*)Cd)[(size_t)row * N + col] = f2b(v);
            }
        }
    }
}

// ---------------- bias precompute: biasM[wtype][head][q][kpad=112] = rel_bias + mask, -1e30 pad ----------------
__global__ __launch_bounds__(256) void biasprep_k(const float* __restrict__ table, u16* __restrict__ biasM) {
    int idx = blockIdx.x * 256 + threadIdx.x;
    int k = idx % 112;
    int t = idx / 112;
    int q = t % 100; t /= 100;
    int head = t & 15, wt = t >> 4;
    float v;
    if (k >= 100) {
        v = -1e30f;
    } else {
        int qi = q / 10, qj = q - qi * 10;
        int ki = k / 10, kj = k - ki * 10;
        int rel = (qi - ki) * 19 + (qj - kj) + 180;   // = qoff - koff + 180
        v = table[rel * 16 + head];
        int rq = ((wt & 2) ? (qi < 5 ? 4 : 8) : 0) + ((wt & 1) ? (qj < 5 ? 1 : 2) : 0);
        int rk = ((wt & 2) ? (ki < 5 ? 4 : 8) : 0) + ((wt & 1) ? (kj < 5 ? 1 : 2) : 0);
        if (rq != rk) v -= 100.0f;
    }
    biasM[idx] = f2b(v);
}

// ---------------- MFMA windowed attention: one WAVE per (window, head) ----------------
// Swapped orientation: S^T[k][q] = K·(s·Q)^T + biasM  (scale folded into wq/bq upstream).
__global__ __launch_bounds__(256, 3) void attn_mfma_k(const u16* __restrict__ Q, const u16* __restrict__ Km,
                                                      const u16* __restrict__ V, const u16* __restrict__ biasM,
                                                      u16* __restrict__ ctx) {
    __shared__ __align__(16) u16 lds[4 * 6144];   // 48KB: 4 waves x (Vt 4096 + P 2048) u16
    int tid = threadIdx.x;
    int wave = tid >> 6, lane = tid & 63;
    int l15 = lane & 15, quad = lane >> 4;
    int bid = blockIdx.x;                 // 1536 blocks = 384 windows x 4
    int win = bid >> 2;
    int head = ((bid & 3) << 2) + wave;   // 4 waves cover 4 heads
    int w48 = win % 48;
    int wh = w48 / 6, ww = w48 - wh * 6;
    int wtype = ((wh == 7) ? 2 : 0) + ((ww == 5) ? 1 : 0);
    size_t base = (size_t)win * 51200 + head * 32;
    u16* Vt = lds + wave * 6144;          // [32 d][128 k] swizzled
    u16* Pl = Vt + 4096;                  // [16 q][128 k] swizzled
    const u16* bptr = biasM + (size_t)(wtype * 16 + head) * 11200;

    // zero Vt logical k in [96,128)
    {
        uint4 z = {0u, 0u, 0u, 0u};
#pragma unroll
        for (int r = 0; r < 2; r++) {
            int c = r * 64 + lane;
            int d = c >> 2, seg = c & 3;
            int k0 = 96 + seg * 8;
            *(uint4*)(Vt + d * 128 + (k0 ^ ((d & 7) << 3))) = z;
        }
        uint2 z2 = {0u, 0u};              // zero P logical k in [112,128)
        *(uint2*)(Pl + l15 * 128 + ((112 + quad * 4) ^ ((l15 & 7) << 3))) = z2;
    }
    // stage V transposed: Vt[d][k] = V[k][d]
#pragma unroll
    for (int r = 0; r < 2; r++) {
        int k = r * 64 + lane;
        if (k < 100) {
            const uint4* vp = (const uint4*)(V + base + (size_t)k * 512);
#pragma unroll
            for (int c = 0; c < 4; c++) {
                uint4 dv = vp[c];
                const u16* e = (const u16*)&dv;
#pragma unroll
                for (int t = 0; t < 8; t++) {
                    int d = c * 8 + t;
                    Vt[d * 128 + (k ^ ((d & 7) << 3))] = e[t];
                }
            }
        }
    }
    // K A-frags (resident)
    bf16x8 kf[7];
#pragma unroll
    for (int i = 0; i < 7; i++) {
        int kr = i * 16 + l15; if (kr > 99) kr = 99;
        kf[i] = *(const bf16x8*)(Km + base + (size_t)kr * 512 + quad * 8);
    }
    // V^T A-frags (resident)
    bf16x8 vf[2][4];
#pragma unroll
    for (int it = 0; it < 2; it++)
#pragma unroll
        for (int ks = 0; ks < 4; ks++) {
            int D = it * 16 + l15;
            vf[it][ks] = *(const bf16x8*)(Vt + D * 128 + ((ks * 32 + quad * 8) ^ ((D & 7) << 3)));
        }

#pragma unroll 1
    for (int j = 0; j < 7; j++) {
        int q = j * 16 + l15;
        int qc = q > 99 ? 99 : q;
        bf16x8 qf = *(const bf16x8*)(Q + base + (size_t)qc * 512 + quad * 8);
        f32x4 s[7];
#pragma unroll
        for (int i = 0; i < 7; i++) {
            uint2 bb = *(const uint2*)(bptr + (size_t)qc * 112 + i * 16 + quad * 4);
            const u16* be = (const u16*)&bb;
            s[i][0] = b2f(be[0]); s[i][1] = b2f(be[1]);
            s[i][2] = b2f(be[2]); s[i][3] = b2f(be[3]);
        }
#pragma unroll
        for (int i = 0; i < 7; i++)
            s[i] = __builtin_amdgcn_mfma_f32_16x16x32_bf16(kf[i], qf, s[i], 0, 0, 0);
        float m = -1e30f;
#pragma unroll
        for (int i = 0; i < 7; i++)
#pragma unroll
            for (int rr = 0; rr < 4; rr++) m = fmaxf(m, s[i][rr]);
        m = fmaxf(m, __shfl_xor(m, 16));
        m = fmaxf(m, __shfl_xor(m, 32));
        float l = 0.f;
#pragma unroll
        for (int i = 0; i < 7; i++)
#pragma unroll
            for (int rr = 0; rr < 4; rr++) { s[i][rr] = __expf(s[i][rr] - m); l += s[i][rr]; }
        l += __shfl_xor(l, 16);
        l += __shfl_xor(l, 32);
#pragma unroll
        for (int i = 0; i < 7; i++) {
            u32 lo, hi;
            asm("v_cvt_pk_bf16_f32 %0, %1, %2" : "=v"(lo) : "v"(s[i][0]), "v"(s[i][1]));
            asm("v_cvt_pk_bf16_f32 %0, %1, %2" : "=v"(hi) : "v"(s[i][2]), "v"(s[i][3]));
            uint2 w; w.x = lo; w.y = hi;
            *(uint2*)(Pl + l15 * 128 + ((i * 16 + quad * 4) ^ ((l15 & 7) << 3))) = w;
        }
        f32x4 o0 = (f32x4){0.f, 0.f, 0.f, 0.f};
        f32x4 o1 = (f32x4){0.f, 0.f, 0.f, 0.f};
#pragma unroll
        for (int ks = 0; ks < 4; ks++) {
            bf16x8 pf = *(const bf16x8*)(Pl + l15 * 128 + ((ks * 32 + quad * 8) ^ ((l15 & 7) << 3)));
            o0 = __builtin_amdgcn_mfma_f32_16x16x32_bf16(vf[0][ks], pf, o0, 0, 0, 0);
            o1 = __builtin_amdgcn_mfma_f32_16x16x32_bf16(vf[1][ks], pf, o1, 0, 0, 0);
        }
        float inv = 1.0f / l;
        if (q < 100) {
            u16* cp = ctx + base + (size_t)q * 512;
            {
                float a0 = o0[0]*inv, a1 = o0[1]*inv, a2 = o0[2]*inv, a3 = o0[3]*inv;
                u32 lo, hi;
                asm("v_cvt_pk_bf16_f32 %0, %1, %2" : "=v"(lo) : "v"(a0), "v"(a1));
                asm("v_cvt_pk_bf16_f32 %0, %1, %2" : "=v"(hi) : "v"(a2), "v"(a3));
                uint2 w; w.x = lo; w.y = hi;
                *(uint2*)(cp + quad * 4) = w;
            }
            {
                float a0 = o1[0]*inv, a1 = o1[1]*inv, a2 = o1[2]*inv, a3 = o1[3]*inv;
                u32 lo, hi;
                asm("v_cvt_pk_bf16_f32 %0, %1, %2" : "=v"(lo) : "v"(a0), "v"(a1));
                asm("v_cvt_pk_bf16_f32 %0, %1, %2" : "=v"(hi) : "v"(a2), "v"(a3));
                uint2 w; w.x = lo; w.y = hi;
                *(uint2*)(cp + 16 + quad * 4) = w;
            }
        }
    }
}

extern "C" void kernel_launch(void* const* d_in, const int* in_sizes, int n_in,
                              void* d_out, int out_size, void* d_ws, size_t ws_size,
                              hipStream_t stream) {
    const float* hidden = (const float*)d_in[0];
    const float* ln1_g  = (const float*)d_in[1];
    const float* ln1_b  = (const float*)d_in[2];
    const float* wq = (const float*)d_in[3];  const float* bq = (const float*)d_in[4];
    const float* wk = (const float*)d_in[5];  const float* bk = (const float*)d_in[6];
    const float* wv = (const float*)d_in[7];  const float* bv = (const float*)d_in[8];
    const float* wo = (const float*)d_in[9];  const float* bo = (const float*)d_in[10];
    const float* rel = (const float*)d_in[11];
    const float* ln2_g = (const float*)d_in[12];
    const float* ln2_b = (const float*)d_in[13];
    const float* w1 = (const float*)d_in[14]; const float* b1 = (const float*)d_in[15];
    const float* w2 = (const float*)d_in[16]; const float* b2 = (const float*)d_in[17];

    // ws: R0,R1,Rh = 3*NTC bf16 (118MB) + weights (+6KB qkv bias). d_out doubles as V / ln2y park.
    //   R0: win -> ctx -> h1 chunk (with R1) ; R1: q -> attn_out ; Rh: k -> hs
    //   d_out lo (bf16): v -> ln2y ; biasM parked at d_out+NTC u16.
    const size_t NTC = 38400ull * 512;
    u16* ws = (u16*)d_ws;
    u16* R0 = ws;
    u16* R1 = ws + NTC;
    u16* Rh = ws + 2 * NTC;
    u16* wqt = ws + 3 * NTC;
    u16* wkt = wqt + 512 * 512;
    u16* wvt = wkt + 512 * 512;       // wqt..wvt contiguous => fused QKV Bt (1536 x 512)
    u16* wot = wvt + 512 * 512;
    u16* w1t = wot + 512 * 512;       // (2048,512)
    u16* w2t = w1t + 1048576;         // (512,2048)
    float* qkvb = (float*)(w2t + 1048576);   // concat bias [1536]
    u16* dlo = (u16*)d_out;           // v, then ln2y (bf16)
    u16* biasM = dlo + NTC;           // [4][16][100][112] bf16
    float* outp = (float*)d_out;

    const float SC = 0.17677669529663689f;   // 1/sqrt(32), folded into wq/bq

    transpose_k<<<dim3(16, 16), 256, 0, stream>>>(wq, wqt, 512, 512, SC);
    transpose_k<<<dim3(16, 16), 256, 0, stream>>>(wk, wkt, 512, 512, 1.0f);
    transpose_k<<<dim3(16, 16), 256, 0, stream>>>(wv, wvt, 512, 512, 1.0f);
    transpose_k<<<dim3(16, 16), 256, 0, stream>>>(wo, wot, 512, 512, 1.0f);
    transpose_k<<<dim3(16, 64), 256, 0, stream>>>(w1, w1t, 512, 2048, 1.0f);
    transpose_k<<<dim3(64, 16), 256, 0, stream>>>(w2, w2t, 2048, 512, 1.0f);
    biascat_k<<<6, 256, 0, stream>>>(bq, bk, bv, qkvb);
    biasprep_k<<<2800, 256, 0, stream>>>(rel, biasM);   // 716800 = 2800*256

    ln1win_k<<<9600, 256, 0, stream>>>(hidden, ln1_g, ln1_b, R0 /*win*/);

    // fused QKV: cols 0..1535 over contiguous wqt|wkt|wvt; outputs routed to R1 / Rh / dlo (stride 512)
    gemm_k<0, 0, 1><<<dim3(150, 6), 512, 0, stream>>>(R0, wqt, qkvb, nullptr,
                                                      R1 /*q*/, Rh /*k*/, dlo /*v*/, 38400, 512, 512);

    attn_mfma_k<<<1536, 256, 0, stream>>>(R1, Rh, dlo, biasM, R0 /*ctx*/);

    gemm_k<0, 0, 0><<<dim3(150, 2), 512, 0, stream>>>(R0, wot, bo, nullptr,
                                                      R1 /*attn_out*/, nullptr, nullptr, 38400, 512, 512);

    resid2_k<<<9600, 256, 0, stream>>>(hidden, R1, ln2_g, ln2_b, Rh /*hs*/, dlo /*ln2y*/);

    // FFN in 2 chunks of 19200 rows, REVERSE order so fp32 out writes never clobber unread bf16 ln2y:
    // chunk mc reads bf16 [mc*19.66MB, +19.66MB); writes fp32 [mc*39.32MB, +39.32MB).
    for (int mc = 1; mc >= 0; mc--) {
        size_t roff = (size_t)mc * 19200 * 512;
        gemm_k<1, 0, 0><<<dim3(75, 8), 512, 0, stream>>>(dlo + roff, w1t, b1, nullptr,
                                                         R0 /*h1*/, nullptr, nullptr, 19200, 2048, 512);
        gemm_k<2, 1, 0><<<dim3(75, 2), 512, 0, stream>>>(R0, w2t, b2, Rh + roff,
                                                         outp + roff, nullptr, nullptr, 19200, 512, 2048);
    }
}

// Round 6
// 729.540 us; speedup vs baseline: 1.0311x; 1.0311x over previous
//
#include <hip/hip_runtime.h>
#include <math.h>

typedef unsigned short u16;
typedef unsigned int u32;
typedef __bf16 bf16x8 __attribute__((ext_vector_type(8)));
typedef float f32x4 __attribute__((ext_vector_type(4)));

__device__ __forceinline__ float b2f(u16 u) { return __uint_as_float(((u32)u) << 16); }
__device__ __forceinline__ u16 f2b(float f) {
    u32 x = __float_as_uint(f);
    return (u16)((x + 0x7FFFu + ((x >> 16) & 1u)) >> 16);
}
__device__ __forceinline__ void load8f(const float* p, size_t idx, float* o) {
    const float4* q = (const float4*)(p + idx);
    float4 a = q[0], b = q[1];
    o[0]=a.x; o[1]=a.y; o[2]=a.z; o[3]=a.w; o[4]=b.x; o[5]=b.y; o[6]=b.z; o[7]=b.w;
}
// async global->LDS, 16B per lane; LDS dest = wave-uniform base + lane*16
__device__ __forceinline__ void gld16(const void* g, void* l) {
    __builtin_amdgcn_global_load_lds(
        (const __attribute__((address_space(1))) u32*)g,
        (__attribute__((address_space(3))) u32*)l, 16, 0, 0);
}

// ---------------- weight transpose+convert: Wt[n][k] = bf16(W[k][n] * scale) ----------------
__global__ __launch_bounds__(256) void transpose_k(const float* __restrict__ Win, u16* __restrict__ Wt,
                                                   int Kd, int Nd, float scale) {
    __shared__ u16 tile[32][33];
    int tx = threadIdx.x & 31, ty = threadIdx.x >> 5;
    int k0 = blockIdx.x << 5, n0 = blockIdx.y << 5;
#pragma unroll
    for (int r = 0; r < 4; r++)
        tile[ty + 8 * r][tx] = f2b(Win[(size_t)(k0 + ty + 8 * r) * Nd + (n0 + tx)] * scale);
    __syncthreads();
#pragma unroll
    for (int r = 0; r < 4; r++)
        Wt[(size_t)(n0 + ty + 8 * r) * Kd + (k0 + tx)] = tile[tx][ty + 8 * r];
}

// ---------------- concat qkv bias (scale folded into q part) ----------------
__global__ __launch_bounds__(256) void biascat_k(const float* __restrict__ bq, const float* __restrict__ bk,
                                                 const float* __restrict__ bv, float* __restrict__ o) {
    int i = blockIdx.x * 256 + threadIdx.x;   // 1536
    float v = (i < 512) ? bq[i] * 0.17677669529663689f : (i < 1024 ? bk[i - 512] : bv[i - 1024]);
    o[i] = v;
}

// ---------------- LN1 (stats fused) + shift + window partition ----------------
__global__ __launch_bounds__(256) void ln1win_k(const float* __restrict__ x, const float* __restrict__ g,
                                                const float* __restrict__ bta, u16* __restrict__ win) {
    int wave = threadIdx.x >> 6, lane = threadIdx.x & 63;
    int token = blockIdx.x * 4 + wave;                  // token-order row
    int b = token / 4800, rem = token - b * 4800;
    int h = rem / 60, w = rem - h * 60;
    int hr = h + 75; if (hr >= 80) hr -= 80;            // (h-5) mod 80 : rolled coord
    int wr = w + 55; if (wr >= 60) wr -= 60;
    int widx = (hr / 10) * 6 + (wr / 10);
    int l = (hr - (hr / 10) * 10) * 10 + (wr - (wr / 10) * 10);
    size_t dstrow = ((size_t)b * 48 + widx) * 100 + l;  // window-order row
    int c0 = lane * 8;
    float v[8]; load8f(x, (size_t)token * 512 + c0, v);
    float s = 0.f, s2 = 0.f;
#pragma unroll
    for (int e = 0; e < 8; e++) { s += v[e]; s2 += v[e] * v[e]; }
#pragma unroll
    for (int o = 32; o > 0; o >>= 1) { s += __shfl_xor(s, o); s2 += __shfl_xor(s2, o); }
    float mean = s * (1.0f / 512.0f);
    float var = fmaxf(s2 * (1.0f / 512.0f) - mean * mean, 0.0f);
    float rstd = rsqrtf(var + 1e-5f);
    uint4 o4; u16* ou = (u16*)&o4;
#pragma unroll
    for (int e = 0; e < 8; e++)
        ou[e] = f2b((v[e] - mean) * rstd * g[c0 + e] + bta[c0 + e]);
    *(uint4*)(win + dstrow * 512 + c0) = o4;
}

// ---------------- window reverse + residual + fused LN2: hs, ln2y ----------------
__global__ __launch_bounds__(256) void resid2_k(const float* __restrict__ shortcut, const u16* __restrict__ attn_out,
                                                const float* __restrict__ g, const float* __restrict__ bta,
                                                u16* __restrict__ hs, u16* __restrict__ ln2y) {
    int wave = threadIdx.x >> 6, lane = threadIdx.x & 63;
    int token = blockIdx.x * 4 + wave;
    int b = token / 4800, rem = token - b * 4800;
    int h = rem / 60, w = rem - h * 60;
    int hr = h + 75; if (hr >= 80) hr -= 80;
    int wr = w + 55; if (wr >= 60) wr -= 60;
    int widx = (hr / 10) * 6 + (wr / 10);
    int l = (hr - (hr / 10) * 10) * 10 + (wr - (wr / 10) * 10);
    size_t arow = ((size_t)b * 48 + widx) * 100 + l;
    int c0 = lane * 8;
    float sv[8]; load8f(shortcut, (size_t)token * 512 + c0, sv);
    uint4 da = *(const uint4*)(attn_out + arow * 512 + c0);
    const u16* au = (const u16*)&da;
    float hv[8]; float s = 0.f, s2 = 0.f;
    uint4 oh; u16* ohu = (u16*)&oh;
#pragma unroll
    for (int e = 0; e < 8; e++) {
        hv[e] = sv[e] + b2f(au[e]);
        s += hv[e]; s2 += hv[e] * hv[e];
        ohu[e] = f2b(hv[e]);
    }
    *(uint4*)(hs + (size_t)token * 512 + c0) = oh;
#pragma unroll
    for (int off = 32; off > 0; off >>= 1) { s += __shfl_xor(s, off); s2 += __shfl_xor(s2, off); }
    float mean = s * (1.0f / 512.0f);
    float var = fmaxf(s2 * (1.0f / 512.0f) - mean * mean, 0.0f);
    float rstd = rsqrtf(var + 1e-5f);
    uint4 oy; u16* oyu = (u16*)&oy;
#pragma unroll
    for (int e = 0; e < 8; e++)
        oyu[e] = f2b((hv[e] - mean) * rstd * g[c0 + e] + bta[c0 + e]);
    *(uint4*)(ln2y + (size_t)token * 512 + c0) = oy;
}

// ================= 256x256 GEMM, full-iteration prefetch, counted vmcnt =================
// 512 thr = 8 waves (2Mx4N), BK=64, LDS 2x64KB double buffer (1 block/CU).
// Schedule (fix for r5's 11% MfmaUtil): ALL 8 loads of tile t+1 issue at TOP of iter t ->
// the vmcnt(8) wait for tile t targets loads issued one FULL iteration (~600+ cyc) earlier,
// not 2 phases (~150 cyc) earlier. 2 barriers/K-tile:
//   B1 after vmcnt drain (tile t resident everywhere);
//   B2 after lgkmcnt(0) (all reads of buf cur done -> next iter may stage into it).
// T2 swizzle (r5-verified, conflicts==0): stage source chunk = (lane&7)^(row&7); read chunk
// (ks*4+quad)^(row&7) -> xk0/xk1. Same mapping as r5 (numerically verified, absmax 0.03125).
template <int EPI, int OF32, int QKV>
__global__ __launch_bounds__(512, 2) void gemm256_k(const u16* __restrict__ A, const u16* __restrict__ Bt,
                                                    const float* __restrict__ bias, const u16* __restrict__ res,
                                                    void* __restrict__ C0, void* __restrict__ C1, void* __restrict__ C2,
                                                    int M, int N, int K) {
    __shared__ __align__(16) u16 As[2][256 * 64];
    __shared__ __align__(16) u16 Bs[2][256 * 64];
    int tid = threadIdx.x;
    int wave = tid >> 6, lane = tid & 63;
    int l15 = lane & 15, quad = lane >> 4;
    int wr = wave >> 2, wc = wave & 3;            // 2 x 4 wave grid

    // XCD-aware chunked bijective swizzle from the true hw dispatch id (x-fastest).
    int gy = gridDim.y;
    int nwg = gridDim.x * gy;
    int lid = blockIdx.x + blockIdx.y * gridDim.x;
    int xcd = lid & 7, loc = lid >> 3;
    int q8 = nwg >> 3, r8 = nwg & 7;
    int wg = (xcd < r8 ? xcd * (q8 + 1) : r8 * (q8 + 1) + (xcd - r8) * q8) + loc;
    int bn = wg % gy, bm = wg / gy;

    f32x4 acc[8][4];
#pragma unroll
    for (int i = 0; i < 8; i++)
#pragma unroll
        for (int j = 0; j < 4; j++) acc[i][j] = (f32x4){0.f, 0.f, 0.f, 0.f};

    const u16* Ab = A + (size_t)(bm * 256) * K;
    const u16* Bb = Bt + (size_t)(bn * 256) * K;

    // staging lane constants: lane covers row wave*8+(lane>>3), source chunk (lane&7)^(row&7)
    int lrow = lane >> 3;
    int cg = (lane & 7) ^ lrow;
    size_t gOff = (size_t)(wave * 8 + lrow) * K + cg * 8;
    // read lane constants
    int e = l15 & 7;
    int xk0 = (quad ^ e) * 8;       // u16 offset of swizzled chunk, ks=0
    int xk1 = xk0 ^ 32;             // ks=1
    int aRow = (wr * 128 + l15) * 64;
    int bRow = (wc * 64 + l15) * 64;

    auto STAGE_A = [&](int b, int kt, int i) {
        gld16(Ab + (size_t)(i * 64) * K + kt + gOff, &As[b][(i * 64 + wave * 8) * 64]);
    };
    auto STAGE_B = [&](int b, int kt, int j) {
        gld16(Bb + (size_t)(j * 64) * K + kt + gOff, &Bs[b][(j * 64 + wave * 8) * 64]);
    };
    auto STAGE8 = [&](int b, int kt) {
        STAGE_B(b, kt, 0); STAGE_B(b, kt, 1); STAGE_B(b, kt, 2); STAGE_B(b, kt, 3);
        STAGE_A(b, kt, 0); STAGE_A(b, kt, 1); STAGE_A(b, kt, 2); STAGE_A(b, kt, 3);
    };

#define MM16(MH)                                                                     \
    do {                                                                             \
        __builtin_amdgcn_s_setprio(1);                                               \
        _Pragma("unroll") for (int i_ = 0; i_ < 4; i_++)                             \
            _Pragma("unroll") for (int n_ = 0; n_ < 4; n_++)                         \
                acc[(MH) * 4 + i_][n_] = __builtin_amdgcn_mfma_f32_16x16x32_bf16(    \
                    a_[i_], b_[n_], acc[(MH) * 4 + i_][n_], 0, 0, 0);                \
        __builtin_amdgcn_s_setprio(0);                                               \
    } while (0)

    int T = K >> 6;   // K-tiles of 64
    STAGE8(0, 0);     // prologue: tile 0 -> buf 0
#pragma unroll 1
    for (int t = 0; t < T; t++) {
        int cur = t & 1, nxt = cur ^ 1;
        if (t + 1 < T) {
            STAGE8(nxt, (t + 1) << 6);                     // prefetch next tile FIRST
            asm volatile("s_waitcnt vmcnt(8)" ::: "memory");   // drain tile t (issued last iter)
        } else {
            asm volatile("s_waitcnt vmcnt(0)" ::: "memory");
        }
        __builtin_amdgcn_s_barrier();                      // tile t resident for all waves
        asm volatile("" ::: "memory");
        bf16x8 a_[4], b_[4];
#pragma unroll
        for (int n = 0; n < 4; n++) b_[n] = *(const bf16x8*)(&Bs[cur][bRow + n * 1024 + xk0]);
#pragma unroll
        for (int i = 0; i < 4; i++) a_[i] = *(const bf16x8*)(&As[cur][aRow + i * 1024 + xk0]);
        MM16(0);
#pragma unroll
        for (int i = 0; i < 4; i++) a_[i] = *(const bf16x8*)(&As[cur][aRow + (4 + i) * 1024 + xk0]);
        MM16(1);
#pragma unroll
        for (int n = 0; n < 4; n++) b_[n] = *(const bf16x8*)(&Bs[cur][bRow + n * 1024 + xk1]);
#pragma unroll
        for (int i = 0; i < 4; i++) a_[i] = *(const bf16x8*)(&As[cur][aRow + i * 1024 + xk1]);
        MM16(0);
#pragma unroll
        for (int i = 0; i < 4; i++) a_[i] = *(const bf16x8*)(&As[cur][aRow + (4 + i) * 1024 + xk1]);
        asm volatile("s_waitcnt lgkmcnt(0)" ::: "memory"); // all my reads of buf cur complete
        __builtin_amdgcn_sched_barrier(0);
        __builtin_amdgcn_s_barrier();                      // everyone done with cur -> next iter may stage it
        asm volatile("" ::: "memory");
        MM16(1);                                           // register-only, runs past barrier
    }
#undef MM16

    // epilogue. C/D frag layout: col = l15, row = quad*4 + rr
    u16* Cd = (u16*)C0;
    if (QKV) {
        int sel = bn >> 1;
        Cd = (sel == 0) ? (u16*)C0 : (sel == 1) ? (u16*)C1 : (u16*)C2;
    }
#pragma unroll
    for (int m = 0; m < 8; m++) {
        int row0 = bm * 256 + wr * 128 + m * 16 + quad * 4;
#pragma unroll
        for (int n = 0; n < 4; n++) {
            int colg = bn * 256 + wc * 64 + n * 16 + l15;
            int col = QKV ? (colg & 511) : colg;
            float bv = bias[colg];
#pragma unroll
            for (int rr = 0; rr < 4; rr++) {
                int row = row0 + rr;
                float v = acc[m][n][rr] + bv;
                if (EPI == 1) {   // tanh-form GELU
                    float zz = 1.5957691216f * (v + 0.044715f * v * v * v);
                    float tt = 1.0f - 2.0f / (__expf(zz) + 1.0f);
                    v = 0.5f * v * (1.0f + tt);
                }
                if (EPI == 2) v += b2f(res[(size_t)row * 512 + col]);
                if (OF32) ((float*)Cd)[(size_t)row * N + col] = v;
                else      ((u16*)Cd)[(size_t)row * N + col] = f2b(v);
            }
        }
    }
}

// ================= 128x128 GEMM (r4-proven), depth-2 pipeline, 3 blocks/CU =================
// For the small-N shapes (N=512) where 256^2 tiles underfill the 256 CUs.
// Only change vs r4: both-sides chunk-XOR (chunk ^= row&3) on stage source + ds_read to cut
// the 7.37M bank-conflict cycles. Same involution pattern as the gemm256 one (verified).
template <int EPI, int OF32>
__global__ __launch_bounds__(256) void gemm128_k(const u16* __restrict__ A, const u16* __restrict__ Bt,
                                                 const float* __restrict__ bias, const u16* __restrict__ res,
                                                 void* __restrict__ C, int M, int N, int K) {
    __shared__ __align__(16) u16 As[3][128 * 32];
    __shared__ __align__(16) u16 Bs[3][128 * 32];
    int tid = threadIdx.x;
    int wave = tid >> 6, lane = tid & 63;
    int l15 = lane & 15, quad = lane >> 4;
    int lq = lane >> 2, lr = lane & 3;
    int wm = (wave >> 1) * 64, wn = (wave & 1) * 64;

    int gy = gridDim.y;
    int nwg = gridDim.x * gy;
    int lid = blockIdx.x + blockIdx.y * gridDim.x;
    int xcd = lid & 7, loc = lid >> 3;
    int q8 = nwg >> 3, r8 = nwg & 7;
    int wg = (xcd < r8 ? xcd * (q8 + 1) : r8 * (q8 + 1) + (xcd - r8) * q8) + loc;
    int bn = wg % gy, bm = wg / gy;

    f32x4 acc[4][4];
#pragma unroll
    for (int i = 0; i < 4; i++)
#pragma unroll
        for (int j = 0; j < 4; j++) acc[i][j] = (f32x4){0.f, 0.f, 0.f, 0.f};

    const u16* Ab = A + (size_t)(bm * 128) * K;
    const u16* Bb = Bt + (size_t)(bn * 128) * K;

    int cgs = (lr ^ (lq & 3)) * 8;          // swizzled source chunk (stage)
    int xrd = (quad ^ (l15 & 3)) * 8;       // swizzled chunk (read)

    int T = K >> 5;
    auto STAGE = [&](int b, int t) {
        int kt = t << 5;
#pragma unroll
        for (int h = 0; h < 2; h++) {
            int r = h * 64 + wave * 16 + lq;
            gld16(Ab + (size_t)r * K + kt + cgs, &As[b][(h * 64 + wave * 16) * 32]);
            gld16(Bb + (size_t)r * K + kt + cgs, &Bs[b][(h * 64 + wave * 16) * 32]);
        }
    };

    STAGE(0, 0);
    STAGE(1, 1);
    for (int t = 0; t < T; t++) {
        int cb = t % 3;
        if (t + 2 < T) STAGE((t + 2) % 3, t + 2);
        if (t + 2 < T)      asm volatile("s_waitcnt vmcnt(8)" ::: "memory");
        else if (t + 1 < T) asm volatile("s_waitcnt vmcnt(4)" ::: "memory");
        else                asm volatile("s_waitcnt vmcnt(0)" ::: "memory");
        __builtin_amdgcn_s_barrier();
        asm volatile("" ::: "memory");
        bf16x8 af[4], bfr[4];
#pragma unroll
        for (int x = 0; x < 4; x++) {
            af[x]  = *(const bf16x8*)(&As[cb][(wm + x * 16 + l15) * 32 + xrd]);
            bfr[x] = *(const bf16x8*)(&Bs[cb][(wn + x * 16 + l15) * 32 + xrd]);
        }
        asm volatile("s_waitcnt lgkmcnt(0)" ::: "memory");
        __builtin_amdgcn_sched_barrier(0);
        __builtin_amdgcn_s_barrier();
        asm volatile("" ::: "memory");
#pragma unroll
        for (int i = 0; i < 4; i++)
#pragma unroll
            for (int j = 0; j < 4; j++)
                acc[i][j] = __builtin_amdgcn_mfma_f32_16x16x32_bf16(af[i], bfr[j], acc[i][j], 0, 0, 0);
    }

    u16* Cd = (u16*)C;
#pragma unroll
    for (int i = 0; i < 4; i++) {
        int row0 = bm * 128 + wm + i * 16 + quad * 4;
#pragma unroll
        for (int j = 0; j < 4; j++) {
            int col = bn * 128 + wn + j * 16 + l15;
            float bv = bias[col];
#pragma unroll
            for (int rr = 0; rr < 4; rr++) {
                int row = row0 + rr;
                float v = acc[i][j][rr] + bv;
                if (EPI == 1) {
                    float zz = 1.5957691216f * (v + 0.044715f * v * v * v);
                    float tt = 1.0f - 2.0f / (__expf(zz) + 1.0f);
                    v = 0.5f * v * (1.0f + tt);
                }
                if (EPI == 2) v += b2f(res[(size_t)row * 512 + col]);
                if (OF32) ((float*)Cd)[(size_t)row * N + col] = v;
                else      ((u16*)Cd)[(size_t)row * N + col] = f2b(v);
            }
        }
    }
}

// ---------------- bias precompute: biasM[wtype][head][q][kpad=112] = rel_bias + mask, -1e30 pad ----------------
__global__ __launch_bounds__(256) void biasprep_k(const float* __restrict__ table, u16* __restrict__ biasM) {
    int idx = blockIdx.x * 256 + threadIdx.x;
    int k = idx % 112;
    int t = idx / 112;
    int q = t % 100; t /= 100;
    int head = t & 15, wt = t >> 4;
    float v;
    if (k >= 100) {
        v = -1e30f;
    } else {
        int qi = q / 10, qj = q - qi * 10;
        int ki = k / 10, kj = k - ki * 10;
        int rel = (qi - ki) * 19 + (qj - kj) + 180;   // = qoff - koff + 180
        v = table[rel * 16 + head];
        int rq = ((wt & 2) ? (qi < 5 ? 4 : 8) : 0) + ((wt & 1) ? (qj < 5 ? 1 : 2) : 0);
        int rk = ((wt & 2) ? (ki < 5 ? 4 : 8) : 0) + ((wt & 1) ? (kj < 5 ? 1 : 2) : 0);
        if (rq != rk) v -= 100.0f;
    }
    biasM[idx] = f2b(v);
}

// ---------------- MFMA windowed attention: one WAVE per (window, head) ----------------
// Swapped orientation: S^T[k][q] = K·(s·Q)^T + biasM  (scale folded into wq/bq upstream).
__global__ __launch_bounds__(256, 3) void attn_mfma_k(const u16* __restrict__ Q, const u16* __restrict__ Km,
                                                      const u16* __restrict__ V, const u16* __restrict__ biasM,
                                                      u16* __restrict__ ctx) {
    __shared__ __align__(16) u16 lds[4 * 6144];   // 48KB: 4 waves x (Vt 4096 + P 2048) u16
    int tid = threadIdx.x;
    int wave = tid >> 6, lane = tid & 63;
    int l15 = lane & 15, quad = lane >> 4;
    int bid = blockIdx.x;                 // 1536 blocks = 384 windows x 4
    int win = bid >> 2;
    int head = ((bid & 3) << 2) + wave;   // 4 waves cover 4 heads
    int w48 = win % 48;
    int wh = w48 / 6, ww = w48 - wh * 6;
    int wtype = ((wh == 7) ? 2 : 0) + ((ww == 5) ? 1 : 0);
    size_t base = (size_t)win * 51200 + head * 32;
    u16* Vt = lds + wave * 6144;          // [32 d][128 k] swizzled
    u16* Pl = Vt + 4096;                  // [16 q][128 k] swizzled
    const u16* bptr = biasM + (size_t)(wtype * 16 + head) * 11200;

    // zero Vt logical k in [96,128)
    {
        uint4 z = {0u, 0u, 0u, 0u};
#pragma unroll
        for (int r = 0; r < 2; r++) {
            int c = r * 64 + lane;
            int d = c >> 2, seg = c & 3;
            int k0 = 96 + seg * 8;
            *(uint4*)(Vt + d * 128 + (k0 ^ ((d & 7) << 3))) = z;
        }
        uint2 z2 = {0u, 0u};              // zero P logical k in [112,128)
        *(uint2*)(Pl + l15 * 128 + ((112 + quad * 4) ^ ((l15 & 7) << 3))) = z2;
    }
    // stage V transposed: Vt[d][k] = V[k][d]
#pragma unroll
    for (int r = 0; r < 2; r++) {
        int k = r * 64 + lane;
        if (k < 100) {
            const uint4* vp = (const uint4*)(V + base + (size_t)k * 512);
#pragma unroll
            for (int c = 0; c < 4; c++) {
                uint4 dv = vp[c];
                const u16* e = (const u16*)&dv;
#pragma unroll
                for (int t = 0; t < 8; t++) {
                    int d = c * 8 + t;
                    Vt[d * 128 + (k ^ ((d & 7) << 3))] = e[t];
                }
            }
        }
    }
    // K A-frags (resident)
    bf16x8 kf[7];
#pragma unroll
    for (int i = 0; i < 7; i++) {
        int kr = i * 16 + l15; if (kr > 99) kr = 99;
        kf[i] = *(const bf16x8*)(Km + base + (size_t)kr * 512 + quad * 8);
    }
    // V^T A-frags (resident)
    bf16x8 vf[2][4];
#pragma unroll
    for (int it = 0; it < 2; it++)
#pragma unroll
        for (int ks = 0; ks < 4; ks++) {
            int D = it * 16 + l15;
            vf[it][ks] = *(const bf16x8*)(Vt + D * 128 + ((ks * 32 + quad * 8) ^ ((D & 7) << 3)));
        }

#pragma unroll 1
    for (int j = 0; j < 7; j++) {
        int q = j * 16 + l15;
        int qc = q > 99 ? 99 : q;
        bf16x8 qf = *(const bf16x8*)(Q + base + (size_t)qc * 512 + quad * 8);
        f32x4 s[7];
#pragma unroll
        for (int i = 0; i < 7; i++) {
            uint2 bb = *(const uint2*)(bptr + (size_t)qc * 112 + i * 16 + quad * 4);
            const u16* be = (const u16*)&bb;
            s[i][0] = b2f(be[0]); s[i][1] = b2f(be[1]);
            s[i][2] = b2f(be[2]); s[i][3] = b2f(be[3]);
        }
#pragma unroll
        for (int i = 0; i < 7; i++)
            s[i] = __builtin_amdgcn_mfma_f32_16x16x32_bf16(kf[i], qf, s[i], 0, 0, 0);
        float m = -1e30f;
#pragma unroll
        for (int i = 0; i < 7; i++)
#pragma unroll
            for (int rr = 0; rr < 4; rr++) m = fmaxf(m, s[i][rr]);
        m = fmaxf(m, __shfl_xor(m, 16));
        m = fmaxf(m, __shfl_xor(m, 32));
        float l = 0.f;
#pragma unroll
        for (int i = 0; i < 7; i++)
#pragma unroll
            for (int rr = 0; rr < 4; rr++) { s[i][rr] = __expf(s[i][rr] - m); l += s[i][rr]; }
        l += __shfl_xor(l, 16);
        l += __shfl_xor(l, 32);
#pragma unroll
        for (int i = 0; i < 7; i++) {
            u32 lo, hi;
            asm("v_cvt_pk_bf16_f32 %0, %1, %2" : "=v"(lo) : "v"(s[i][0]), "v"(s[i][1]));
            asm("v_cvt_pk_bf16_f32 %0, %1, %2" : "=v"(hi) : "v"(s[i][2]), "v"(s[i][3]));
            uint2 w; w.x = lo; w.y = hi;
            *(uint2*)(Pl + l15 * 128 + ((i * 16 + quad * 4) ^ ((l15 & 7) << 3))) = w;
        }
        f32x4 o0 = (f32x4){0.f, 0.f, 0.f, 0.f};
        f32x4 o1 = (f32x4){0.f, 0.f, 0.f, 0.f};
#pragma unroll
        for (int ks = 0; ks < 4; ks++) {
            bf16x8 pf = *(const bf16x8*)(Pl + l15 * 128 + ((ks * 32 + quad * 8) ^ ((l15 & 7) << 3)));
            o0 = __builtin_amdgcn_mfma_f32_16x16x32_bf16(vf[0][ks], pf, o0, 0, 0, 0);
            o1 = __builtin_amdgcn_mfma_f32_16x16x32_bf16(vf[1][ks], pf, o1, 0, 0, 0);
        }
        float inv = 1.0f / l;
        if (q < 100) {
            u16* cp = ctx + base + (size_t)q * 512;
            {
                float a0 = o0[0]*inv, a1 = o0[1]*inv, a2 = o0[2]*inv, a3 = o0[3]*inv;
                u32 lo, hi;
                asm("v_cvt_pk_bf16_f32 %0, %1, %2" : "=v"(lo) : "v"(a0), "v"(a1));
                asm("v_cvt_pk_bf16_f32 %0, %1, %2" : "=v"(hi) : "v"(a2), "v"(a3));
                uint2 w; w.x = lo; w.y = hi;
                *(uint2*)(cp + quad * 4) = w;
            }
            {
                float a0 = o1[0]*inv, a1 = o1[1]*inv, a2 = o1[2]*inv, a3 = o1[3]*inv;
                u32 lo, hi;
                asm("v_cvt_pk_bf16_f32 %0, %1, %2" : "=v"(lo) : "v"(a0), "v"(a1));
                asm("v_cvt_pk_bf16_f32 %0, %1, %2" : "=v"(hi) : "v"(a2), "v"(a3));
                uint2 w; w.x = lo; w.y = hi;
                *(uint2*)(cp + 16 + quad * 4) = w;
            }
        }
    }
}

extern "C" void kernel_launch(void* const* d_in, const int* in_sizes, int n_in,
                              void* d_out, int out_size, void* d_ws, size_t ws_size,
                              hipStream_t stream) {
    const float* hidden = (const float*)d_in[0];
    const float* ln1_g  = (const float*)d_in[1];
    const float* ln1_b  = (const float*)d_in[2];
    const float* wq = (const float*)d_in[3];  const float* bq = (const float*)d_in[4];
    const float* wk = (const float*)d_in[5];  const float* bk = (const float*)d_in[6];
    const float* wv = (const float*)d_in[7];  const float* bv = (const float*)d_in[8];
    const float* wo = (const float*)d_in[9];  const float* bo = (const float*)d_in[10];
    const float* rel = (const float*)d_in[11];
    const float* ln2_g = (const float*)d_in[12];
    const float* ln2_b = (const float*)d_in[13];
    const float* w1 = (const float*)d_in[14]; const float* b1 = (const float*)d_in[15];
    const float* w2 = (const float*)d_in[16]; const float* b2 = (const float*)d_in[17];

    // ws: R0,R1,Rh = 3*NTC bf16 (118MB) + weights (+6KB qkv bias). d_out doubles as V / ln2y park.
    //   R0: win -> ctx -> h1 chunk ; R1: q -> attn_out ; Rh: k -> hs
    //   d_out lo (bf16): v -> ln2y ; biasM parked at d_out+NTC u16.
    const size_t NTC = 38400ull * 512;
    u16* ws = (u16*)d_ws;
    u16* R0 = ws;
    u16* R1 = ws + NTC;
    u16* Rh = ws + 2 * NTC;
    u16* wqt = ws + 3 * NTC;
    u16* wkt = wqt + 512 * 512;
    u16* wvt = wkt + 512 * 512;       // wqt..wvt contiguous => fused QKV Bt (1536 x 512)
    u16* wot = wvt + 512 * 512;
    u16* w1t = wot + 512 * 512;       // (2048,512)
    u16* w2t = w1t + 1048576;         // (512,2048)
    float* qkvb = (float*)(w2t + 1048576);   // concat bias [1536]
    u16* dlo = (u16*)d_out;           // v, then ln2y (bf16)
    u16* biasM = dlo + NTC;           // [4][16][100][112] bf16
    float* outp = (float*)d_out;

    const float SC = 0.17677669529663689f;   // 1/sqrt(32), folded into wq/bq

    transpose_k<<<dim3(16, 16), 256, 0, stream>>>(wq, wqt, 512, 512, SC);
    transpose_k<<<dim3(16, 16), 256, 0, stream>>>(wk, wkt, 512, 512, 1.0f);
    transpose_k<<<dim3(16, 16), 256, 0, stream>>>(wv, wvt, 512, 512, 1.0f);
    transpose_k<<<dim3(16, 16), 256, 0, stream>>>(wo, wot, 512, 512, 1.0f);
    transpose_k<<<dim3(16, 64), 256, 0, stream>>>(w1, w1t, 512, 2048, 1.0f);
    transpose_k<<<dim3(64, 16), 256, 0, stream>>>(w2, w2t, 2048, 512, 1.0f);
    biascat_k<<<6, 256, 0, stream>>>(bq, bk, bv, qkvb);
    biasprep_k<<<2800, 256, 0, stream>>>(rel, biasM);   // 716800 = 2800*256

    ln1win_k<<<9600, 256, 0, stream>>>(hidden, ln1_g, ln1_b, R0 /*win*/);

    // fused QKV (256^2, 900 blocks): cols 0..1535 over contiguous wqt|wkt|wvt -> R1 / Rh / dlo
    gemm256_k<0, 0, 1><<<dim3(150, 6), 512, 0, stream>>>(R0, wqt, qkvb, nullptr,
                                                         R1 /*q*/, Rh /*k*/, dlo /*v*/, 38400, 512, 512);

    attn_mfma_k<<<1536, 256, 0, stream>>>(R1, Rh, dlo, biasM, R0 /*ctx*/);

    // wo (N=512 -> 128^2, 1200 blocks, 3 blocks/CU)
    gemm128_k<0, 0><<<dim3(300, 4), 256, 0, stream>>>(R0, wot, bo, nullptr,
                                                      R1 /*attn_out*/, 38400, 512, 512);

    resid2_k<<<9600, 256, 0, stream>>>(hidden, R1, ln2_g, ln2_b, Rh /*hs*/, dlo /*ln2y*/);

    // FFN in 2 chunks of 19200 rows, REVERSE order so fp32 out writes never clobber unread bf16 ln2y:
    // chunk mc reads bf16 [mc*19.66MB, +19.66MB); writes fp32 [mc*39.32MB, +39.32MB).
    for (int mc = 1; mc >= 0; mc--) {
        size_t roff = (size_t)mc * 19200 * 512;
        // h1 (N=2048 -> 256^2, 600 blocks)
        gemm256_k<1, 0, 0><<<dim3(75, 8), 512, 0, stream>>>(dlo + roff, w1t, b1, nullptr,
                                                            R0 /*h1*/, nullptr, nullptr, 19200, 2048, 512);
        // out (N=512 -> 128^2, 600 blocks)
        gemm128_k<2, 1><<<dim3(150, 4), 256, 0, stream>>>(R0, w2t, b2, Rh + roff,
                                                          outp + roff, 19200, 512, 2048);
    }
}

// Round 7
// 684.964 us; speedup vs baseline: 1.0982x; 1.0651x over previous
//
#include <hip/hip_runtime.h>
#include <math.h>

typedef unsigned short u16;
typedef unsigned int u32;
typedef __bf16 bf16x8 __attribute__((ext_vector_type(8)));
typedef float f32x4 __attribute__((ext_vector_type(4)));

__device__ __forceinline__ float b2f(u16 u) { return __uint_as_float(((u32)u) << 16); }
__device__ __forceinline__ u16 f2b(float f) {
    u32 x = __float_as_uint(f);
    return (u16)((x + 0x7FFFu + ((x >> 16) & 1u)) >> 16);
}
__device__ __forceinline__ void load8f(const float* p, size_t idx, float* o) {
    const float4* q = (const float4*)(p + idx);
    float4 a = q[0], b = q[1];
    o[0]=a.x; o[1]=a.y; o[2]=a.z; o[3]=a.w; o[4]=b.x; o[5]=b.y; o[6]=b.z; o[7]=b.w;
}
// async global->LDS, 16B per lane; LDS dest = wave-uniform base + lane*16
__device__ __forceinline__ void gld16(const void* g, void* l) {
    __builtin_amdgcn_global_load_lds(
        (const __attribute__((address_space(1))) u32*)g,
        (__attribute__((address_space(3))) u32*)l, 16, 0, 0);
}

// ---------------- weight transpose+convert: Wt[n][k] = bf16(W[k][n] * scale) ----------------
__global__ __launch_bounds__(256) void transpose_k(const float* __restrict__ Win, u16* __restrict__ Wt,
                                                   int Kd, int Nd, float scale) {
    __shared__ u16 tile[32][33];
    int tx = threadIdx.x & 31, ty = threadIdx.x >> 5;
    int k0 = blockIdx.x << 5, n0 = blockIdx.y << 5;
#pragma unroll
    for (int r = 0; r < 4; r++)
        tile[ty + 8 * r][tx] = f2b(Win[(size_t)(k0 + ty + 8 * r) * Nd + (n0 + tx)] * scale);
    __syncthreads();
#pragma unroll
    for (int r = 0; r < 4; r++)
        Wt[(size_t)(n0 + ty + 8 * r) * Kd + (k0 + tx)] = tile[tx][ty + 8 * r];
}

// ---------------- concat qkv bias (scale folded into q part) ----------------
__global__ __launch_bounds__(256) void biascat_k(const float* __restrict__ bq, const float* __restrict__ bk,
                                                 const float* __restrict__ bv, float* __restrict__ o) {
    int i = blockIdx.x * 256 + threadIdx.x;   // 1536
    float v = (i < 512) ? bq[i] * 0.17677669529663689f : (i < 1024 ? bk[i - 512] : bv[i - 1024]);
    o[i] = v;
}

// ---------------- LN1 (stats fused) + shift + window partition ----------------
__global__ __launch_bounds__(256) void ln1win_k(const float* __restrict__ x, const float* __restrict__ g,
                                                const float* __restrict__ bta, u16* __restrict__ win) {
    int wave = threadIdx.x >> 6, lane = threadIdx.x & 63;
    int token = blockIdx.x * 4 + wave;                  // token-order row
    int b = token / 4800, rem = token - b * 4800;
    int h = rem / 60, w = rem - h * 60;
    int hr = h + 75; if (hr >= 80) hr -= 80;            // (h-5) mod 80 : rolled coord
    int wr = w + 55; if (wr >= 60) wr -= 60;
    int widx = (hr / 10) * 6 + (wr / 10);
    int l = (hr - (hr / 10) * 10) * 10 + (wr - (wr / 10) * 10);
    size_t dstrow = ((size_t)b * 48 + widx) * 100 + l;  // window-order row
    int c0 = lane * 8;
    float v[8]; load8f(x, (size_t)token * 512 + c0, v);
    float s = 0.f, s2 = 0.f;
#pragma unroll
    for (int e = 0; e < 8; e++) { s += v[e]; s2 += v[e] * v[e]; }
#pragma unroll
    for (int o = 32; o > 0; o >>= 1) { s += __shfl_xor(s, o); s2 += __shfl_xor(s2, o); }
    float mean = s * (1.0f / 512.0f);
    float var = fmaxf(s2 * (1.0f / 512.0f) - mean * mean, 0.0f);
    float rstd = rsqrtf(var + 1e-5f);
    uint4 o4; u16* ou = (u16*)&o4;
#pragma unroll
    for (int e = 0; e < 8; e++)
        ou[e] = f2b((v[e] - mean) * rstd * g[c0 + e] + bta[c0 + e]);
    *(uint4*)(win + dstrow * 512 + c0) = o4;
}

// ---------------- window reverse + residual + fused LN2: hs, ln2y ----------------
__global__ __launch_bounds__(256) void resid2_k(const float* __restrict__ shortcut, const u16* __restrict__ attn_out,
                                                const float* __restrict__ g, const float* __restrict__ bta,
                                                u16* __restrict__ hs, u16* __restrict__ ln2y) {
    int wave = threadIdx.x >> 6, lane = threadIdx.x & 63;
    int token = blockIdx.x * 4 + wave;
    int b = token / 4800, rem = token - b * 4800;
    int h = rem / 60, w = rem - h * 60;
    int hr = h + 75; if (hr >= 80) hr -= 80;
    int wr = w + 55; if (wr >= 60) wr -= 60;
    int widx = (hr / 10) * 6 + (wr / 10);
    int l = (hr - (hr / 10) * 10) * 10 + (wr - (wr / 10) * 10);
    size_t arow = ((size_t)b * 48 + widx) * 100 + l;
    int c0 = lane * 8;
    float sv[8]; load8f(shortcut, (size_t)token * 512 + c0, sv);
    uint4 da = *(const uint4*)(attn_out + arow * 512 + c0);
    const u16* au = (const u16*)&da;
    float hv[8]; float s = 0.f, s2 = 0.f;
    uint4 oh; u16* ohu = (u16*)&oh;
#pragma unroll
    for (int e = 0; e < 8; e++) {
        hv[e] = sv[e] + b2f(au[e]);
        s += hv[e]; s2 += hv[e] * hv[e];
        ohu[e] = f2b(hv[e]);
    }
    *(uint4*)(hs + (size_t)token * 512 + c0) = oh;
#pragma unroll
    for (int off = 32; off > 0; off >>= 1) { s += __shfl_xor(s, off); s2 += __shfl_xor(s2, off); }
    float mean = s * (1.0f / 512.0f);
    float var = fmaxf(s2 * (1.0f / 512.0f) - mean * mean, 0.0f);
    float rstd = rsqrtf(var + 1e-5f);
    uint4 oy; u16* oyu = (u16*)&oy;
#pragma unroll
    for (int e = 0; e < 8; e++)
        oyu[e] = f2b((hv[e] - mean) * rstd * g[c0 + e] + bta[c0 + e]);
    *(uint4*)(ln2y + (size_t)token * 512 + c0) = oy;
}

// ================= 256x256 GEMM, full-iteration prefetch, counted vmcnt =================
// (r6-proven: h1 141 -> <98 us.) 512 thr = 8 waves (2Mx4N), BK=64, LDS 2x64KB dbuf.
// All 8 loads of tile t+1 issue at TOP of iter t -> vmcnt(8) waits loads issued one full
// iteration earlier. 2 barriers/K-tile. T2 swizzle verified (conflicts == 0).
template <int EPI, int OF32, int QKV>
__global__ __launch_bounds__(512, 2) void gemm256_k(const u16* __restrict__ A, const u16* __restrict__ Bt,
                                                    const float* __restrict__ bias, const u16* __restrict__ res,
                                                    void* __restrict__ C0, void* __restrict__ C1, void* __restrict__ C2,
                                                    int M, int N, int K) {
    __shared__ __align__(16) u16 As[2][256 * 64];
    __shared__ __align__(16) u16 Bs[2][256 * 64];
    int tid = threadIdx.x;
    int wave = tid >> 6, lane = tid & 63;
    int l15 = lane & 15, quad = lane >> 4;
    int wr = wave >> 2, wc = wave & 3;            // 2 x 4 wave grid

    int gy = gridDim.y;
    int nwg = gridDim.x * gy;
    int lid = blockIdx.x + blockIdx.y * gridDim.x;
    int xcd = lid & 7, loc = lid >> 3;
    int q8 = nwg >> 3, r8 = nwg & 7;
    int wg = (xcd < r8 ? xcd * (q8 + 1) : r8 * (q8 + 1) + (xcd - r8) * q8) + loc;
    int bn = wg % gy, bm = wg / gy;

    f32x4 acc[8][4];
#pragma unroll
    for (int i = 0; i < 8; i++)
#pragma unroll
        for (int j = 0; j < 4; j++) acc[i][j] = (f32x4){0.f, 0.f, 0.f, 0.f};

    const u16* Ab = A + (size_t)(bm * 256) * K;
    const u16* Bb = Bt + (size_t)(bn * 256) * K;

    int lrow = lane >> 3;
    int cg = (lane & 7) ^ lrow;
    size_t gOff = (size_t)(wave * 8 + lrow) * K + cg * 8;
    int e = l15 & 7;
    int xk0 = (quad ^ e) * 8;
    int xk1 = xk0 ^ 32;
    int aRow = (wr * 128 + l15) * 64;
    int bRow = (wc * 64 + l15) * 64;

    auto STAGE_A = [&](int b, int kt, int i) {
        gld16(Ab + (size_t)(i * 64) * K + kt + gOff, &As[b][(i * 64 + wave * 8) * 64]);
    };
    auto STAGE_B = [&](int b, int kt, int j) {
        gld16(Bb + (size_t)(j * 64) * K + kt + gOff, &Bs[b][(j * 64 + wave * 8) * 64]);
    };
    auto STAGE8 = [&](int b, int kt) {
        STAGE_B(b, kt, 0); STAGE_B(b, kt, 1); STAGE_B(b, kt, 2); STAGE_B(b, kt, 3);
        STAGE_A(b, kt, 0); STAGE_A(b, kt, 1); STAGE_A(b, kt, 2); STAGE_A(b, kt, 3);
    };

#define MM16(MH)                                                                     \
    do {                                                                             \
        __builtin_amdgcn_s_setprio(1);                                               \
        _Pragma("unroll") for (int i_ = 0; i_ < 4; i_++)                             \
            _Pragma("unroll") for (int n_ = 0; n_ < 4; n_++)                         \
                acc[(MH) * 4 + i_][n_] = __builtin_amdgcn_mfma_f32_16x16x32_bf16(    \
                    a_[i_], b_[n_], acc[(MH) * 4 + i_][n_], 0, 0, 0);                \
        __builtin_amdgcn_s_setprio(0);                                               \
    } while (0)

    int T = K >> 6;
    STAGE8(0, 0);
#pragma unroll 1
    for (int t = 0; t < T; t++) {
        int cur = t & 1, nxt = cur ^ 1;
        if (t + 1 < T) {
            STAGE8(nxt, (t + 1) << 6);
            asm volatile("s_waitcnt vmcnt(8)" ::: "memory");
        } else {
            asm volatile("s_waitcnt vmcnt(0)" ::: "memory");
        }
        __builtin_amdgcn_s_barrier();
        asm volatile("" ::: "memory");
        bf16x8 a_[4], b_[4];
#pragma unroll
        for (int n = 0; n < 4; n++) b_[n] = *(const bf16x8*)(&Bs[cur][bRow + n * 1024 + xk0]);
#pragma unroll
        for (int i = 0; i < 4; i++) a_[i] = *(const bf16x8*)(&As[cur][aRow + i * 1024 + xk0]);
        MM16(0);
#pragma unroll
        for (int i = 0; i < 4; i++) a_[i] = *(const bf16x8*)(&As[cur][aRow + (4 + i) * 1024 + xk0]);
        MM16(1);
#pragma unroll
        for (int n = 0; n < 4; n++) b_[n] = *(const bf16x8*)(&Bs[cur][bRow + n * 1024 + xk1]);
#pragma unroll
        for (int i = 0; i < 4; i++) a_[i] = *(const bf16x8*)(&As[cur][aRow + i * 1024 + xk1]);
        MM16(0);
#pragma unroll
        for (int i = 0; i < 4; i++) a_[i] = *(const bf16x8*)(&As[cur][aRow + (4 + i) * 1024 + xk1]);
        asm volatile("s_waitcnt lgkmcnt(0)" ::: "memory");
        __builtin_amdgcn_sched_barrier(0);
        __builtin_amdgcn_s_barrier();
        asm volatile("" ::: "memory");
        MM16(1);
    }
#undef MM16

    u16* Cd = (u16*)C0;
    if (QKV) {
        int sel = bn >> 1;
        Cd = (sel == 0) ? (u16*)C0 : (sel == 1) ? (u16*)C1 : (u16*)C2;
    }
#pragma unroll
    for (int m = 0; m < 8; m++) {
        int row0 = bm * 256 + wr * 128 + m * 16 + quad * 4;
#pragma unroll
        for (int n = 0; n < 4; n++) {
            int colg = bn * 256 + wc * 64 + n * 16 + l15;
            int col = QKV ? (colg & 511) : colg;
            float bv = bias[colg];
#pragma unroll
            for (int rr = 0; rr < 4; rr++) {
                int row = row0 + rr;
                float v = acc[m][n][rr] + bv;
                if (EPI == 1) {
                    float zz = 1.5957691216f * (v + 0.044715f * v * v * v);
                    float tt = 1.0f - 2.0f / (__expf(zz) + 1.0f);
                    v = 0.5f * v * (1.0f + tt);
                }
                if (EPI == 2) v += b2f(res[(size_t)row * 512 + col]);
                if (OF32) ((float*)Cd)[(size_t)row * N + col] = v;
                else      ((u16*)Cd)[(size_t)row * N + col] = f2b(v);
            }
        }
    }
}

// ================= 128x128 GEMM, BK=64, same full-iteration-prefetch schedule =================
// Half-size port of gemm256 (replaces the BK=32 depth-2 kernel: its 64B rows made the chunk-XOR
// only 4-way effective -> 4.9M conflicts, and its ~350cyc prefetch distance undershot HBM latency).
// 256 thr = 4 waves (2x2), wave tile 64x64, LDS 2x32KB = 64KB -> 2 blocks/CU for cross-block
// latency hiding. 128B rows -> chunk^(row&7) swizzle identical to gemm256 (conflict-free, 2-way max).
template <int EPI, int OF32>
__global__ __launch_bounds__(256, 2) void gemmB_k(const u16* __restrict__ A, const u16* __restrict__ Bt,
                                                  const float* __restrict__ bias, const u16* __restrict__ res,
                                                  void* __restrict__ C, int M, int N, int K) {
    __shared__ __align__(16) u16 As[2][128 * 64];
    __shared__ __align__(16) u16 Bs[2][128 * 64];
    int tid = threadIdx.x;
    int wave = tid >> 6, lane = tid & 63;
    int l15 = lane & 15, quad = lane >> 4;
    int wr = wave >> 1, wc = wave & 1;            // 2 x 2 wave grid

    int gy = gridDim.y;
    int nwg = gridDim.x * gy;
    int lid = blockIdx.x + blockIdx.y * gridDim.x;
    int xcd = lid & 7, loc = lid >> 3;
    int q8 = nwg >> 3, r8 = nwg & 7;
    int wg = (xcd < r8 ? xcd * (q8 + 1) : r8 * (q8 + 1) + (xcd - r8) * q8) + loc;
    int bn = wg % gy, bm = wg / gy;

    f32x4 acc[4][4];
#pragma unroll
    for (int i = 0; i < 4; i++)
#pragma unroll
        for (int j = 0; j < 4; j++) acc[i][j] = (f32x4){0.f, 0.f, 0.f, 0.f};

    const u16* Ab = A + (size_t)(bm * 128) * K;
    const u16* Bb = Bt + (size_t)(bn * 128) * K;

    // staging: call i covers rows i*32 + wave*8 + (lane>>3); source chunk (lane&7)^(row&7)
    int lrow = lane >> 3;
    int cg = (lane & 7) ^ lrow;
    size_t gOff = (size_t)(wave * 8 + lrow) * K + cg * 8;
    // read: LDS[row][c] holds global chunk c^(row&7); want chunk ks*4+quad at row (..+l15)
    int e = l15 & 7;
    int xk0 = (quad ^ e) * 8;
    int xk1 = xk0 ^ 32;
    int aRow = (wr * 64 + l15) * 64;
    int bRow = (wc * 64 + l15) * 64;

    auto STAGE_A = [&](int b, int kt, int i) {
        gld16(Ab + (size_t)(i * 32) * K + kt + gOff, &As[b][(i * 32 + wave * 8) * 64]);
    };
    auto STAGE_B = [&](int b, int kt, int j) {
        gld16(Bb + (size_t)(j * 32) * K + kt + gOff, &Bs[b][(j * 32 + wave * 8) * 64]);
    };
    auto STAGE8 = [&](int b, int kt) {
        STAGE_B(b, kt, 0); STAGE_B(b, kt, 1); STAGE_B(b, kt, 2); STAGE_B(b, kt, 3);
        STAGE_A(b, kt, 0); STAGE_A(b, kt, 1); STAGE_A(b, kt, 2); STAGE_A(b, kt, 3);
    };

#define MMALL()                                                                      \
    do {                                                                             \
        __builtin_amdgcn_s_setprio(1);                                               \
        _Pragma("unroll") for (int i_ = 0; i_ < 4; i_++)                             \
            _Pragma("unroll") for (int n_ = 0; n_ < 4; n_++)                         \
                acc[i_][n_] = __builtin_amdgcn_mfma_f32_16x16x32_bf16(               \
                    a_[i_], b_[n_], acc[i_][n_], 0, 0, 0);                           \
        __builtin_amdgcn_s_setprio(0);                                               \
    } while (0)

    int T = K >> 6;   // K-tiles of 64 (K in {512, 2048})
    STAGE8(0, 0);
#pragma unroll 1
    for (int t = 0; t < T; t++) {
        int cur = t & 1, nxt = cur ^ 1;
        if (t + 1 < T) {
            STAGE8(nxt, (t + 1) << 6);
            asm volatile("s_waitcnt vmcnt(8)" ::: "memory");
        } else {
            asm volatile("s_waitcnt vmcnt(0)" ::: "memory");
        }
        __builtin_amdgcn_s_barrier();
        asm volatile("" ::: "memory");
        bf16x8 a_[4], b_[4];
#pragma unroll
        for (int n = 0; n < 4; n++) b_[n] = *(const bf16x8*)(&Bs[cur][bRow + n * 1024 + xk0]);
#pragma unroll
        for (int i = 0; i < 4; i++) a_[i] = *(const bf16x8*)(&As[cur][aRow + i * 1024 + xk0]);
        MMALL();
#pragma unroll
        for (int n = 0; n < 4; n++) b_[n] = *(const bf16x8*)(&Bs[cur][bRow + n * 1024 + xk1]);
#pragma unroll
        for (int i = 0; i < 4; i++) a_[i] = *(const bf16x8*)(&As[cur][aRow + i * 1024 + xk1]);
        asm volatile("s_waitcnt lgkmcnt(0)" ::: "memory");
        __builtin_amdgcn_sched_barrier(0);
        __builtin_amdgcn_s_barrier();
        asm volatile("" ::: "memory");
        MMALL();
    }
#undef MMALL

    u16* Cd = (u16*)C;
#pragma unroll
    for (int i = 0; i < 4; i++) {
        int row0 = bm * 128 + wr * 64 + i * 16 + quad * 4;
#pragma unroll
        for (int j = 0; j < 4; j++) {
            int col = bn * 128 + wc * 64 + j * 16 + l15;
            float bv = bias[col];
#pragma unroll
            for (int rr = 0; rr < 4; rr++) {
                int row = row0 + rr;
                float v = acc[i][j][rr] + bv;
                if (EPI == 1) {
                    float zz = 1.5957691216f * (v + 0.044715f * v * v * v);
                    float tt = 1.0f - 2.0f / (__expf(zz) + 1.0f);
                    v = 0.5f * v * (1.0f + tt);
                }
                if (EPI == 2) v += b2f(res[(size_t)row * 512 + col]);
                if (OF32) ((float*)Cd)[(size_t)row * N + col] = v;
                else      ((u16*)Cd)[(size_t)row * N + col] = f2b(v);
            }
        }
    }
}

// ---------------- bias precompute: biasM[wtype][head][q][kpad=112] = rel_bias + mask, -1e30 pad ----------------
__global__ __launch_bounds__(256) void biasprep_k(const float* __restrict__ table, u16* __restrict__ biasM) {
    int idx = blockIdx.x * 256 + threadIdx.x;
    int k = idx % 112;
    int t = idx / 112;
    int q = t % 100; t /= 100;
    int head = t & 15, wt = t >> 4;
    float v;
    if (k >= 100) {
        v = -1e30f;
    } else {
        int qi = q / 10, qj = q - qi * 10;
        int ki = k / 10, kj = k - ki * 10;
        int rel = (qi - ki) * 19 + (qj - kj) + 180;   // = qoff - koff + 180
        v = table[rel * 16 + head];
        int rq = ((wt & 2) ? (qi < 5 ? 4 : 8) : 0) + ((wt & 1) ? (qj < 5 ? 1 : 2) : 0);
        int rk = ((wt & 2) ? (ki < 5 ? 4 : 8) : 0) + ((wt & 1) ? (kj < 5 ? 1 : 2) : 0);
        if (rq != rk) v -= 100.0f;
    }
    biasM[idx] = f2b(v);
}

// ---------------- MFMA windowed attention: one WAVE per (window, head) ----------------
// Swapped orientation: S^T[k][q] = K·(s·Q)^T + biasM  (scale folded into wq/bq upstream).
__global__ __launch_bounds__(256, 3) void attn_mfma_k(const u16* __restrict__ Q, const u16* __restrict__ Km,
                                                      const u16* __restrict__ V, const u16* __restrict__ biasM,
                                                      u16* __restrict__ ctx) {
    __shared__ __align__(16) u16 lds[4 * 6144];   // 48KB: 4 waves x (Vt 4096 + P 2048) u16
    int tid = threadIdx.x;
    int wave = tid >> 6, lane = tid & 63;
    int l15 = lane & 15, quad = lane >> 4;
    int bid = blockIdx.x;                 // 1536 blocks = 384 windows x 4
    int win = bid >> 2;
    int head = ((bid & 3) << 2) + wave;   // 4 waves cover 4 heads
    int w48 = win % 48;
    int wh = w48 / 6, ww = w48 - wh * 6;
    int wtype = ((wh == 7) ? 2 : 0) + ((ww == 5) ? 1 : 0);
    size_t base = (size_t)win * 51200 + head * 32;
    u16* Vt = lds + wave * 6144;          // [32 d][128 k] swizzled
    u16* Pl = Vt + 4096;                  // [16 q][128 k] swizzled
    const u16* bptr = biasM + (size_t)(wtype * 16 + head) * 11200;

    // zero Vt logical k in [96,128)
    {
        uint4 z = {0u, 0u, 0u, 0u};
#pragma unroll
        for (int r = 0; r < 2; r++) {
            int c = r * 64 + lane;
            int d = c >> 2, seg = c & 3;
            int k0 = 96 + seg * 8;
            *(uint4*)(Vt + d * 128 + (k0 ^ ((d & 7) << 3))) = z;
        }
        uint2 z2 = {0u, 0u};              // zero P logical k in [112,128)
        *(uint2*)(Pl + l15 * 128 + ((112 + quad * 4) ^ ((l15 & 7) << 3))) = z2;
    }
    // stage V transposed: Vt[d][k] = V[k][d]
#pragma unroll
    for (int r = 0; r < 2; r++) {
        int k = r * 64 + lane;
        if (k < 100) {
            const uint4* vp = (const uint4*)(V + base + (size_t)k * 512);
#pragma unroll
            for (int c = 0; c < 4; c++) {
                uint4 dv = vp[c];
                const u16* e = (const u16*)&dv;
#pragma unroll
                for (int t = 0; t < 8; t++) {
                    int d = c * 8 + t;
                    Vt[d * 128 + (k ^ ((d & 7) << 3))] = e[t];
                }
            }
        }
    }
    // K A-frags (resident)
    bf16x8 kf[7];
#pragma unroll
    for (int i = 0; i < 7; i++) {
        int kr = i * 16 + l15; if (kr > 99) kr = 99;
        kf[i] = *(const bf16x8*)(Km + base + (size_t)kr * 512 + quad * 8);
    }
    // V^T A-frags (resident)
    bf16x8 vf[2][4];
#pragma unroll
    for (int it = 0; it < 2; it++)
#pragma unroll
        for (int ks = 0; ks < 4; ks++) {
            int D = it * 16 + l15;
            vf[it][ks] = *(const bf16x8*)(Vt + D * 128 + ((ks * 32 + quad * 8) ^ ((D & 7) << 3)));
        }

#pragma unroll 1
    for (int j = 0; j < 7; j++) {
        int q = j * 16 + l15;
        int qc = q > 99 ? 99 : q;
        bf16x8 qf = *(const bf16x8*)(Q + base + (size_t)qc * 512 + quad * 8);
        f32x4 s[7];
#pragma unroll
        for (int i = 0; i < 7; i++) {
            uint2 bb = *(const uint2*)(bptr + (size_t)qc * 112 + i * 16 + quad * 4);
            const u16* be = (const u16*)&bb;
            s[i][0] = b2f(be[0]); s[i][1] = b2f(be[1]);
            s[i][2] = b2f(be[2]); s[i][3] = b2f(be[3]);
        }
#pragma unroll
        for (int i = 0; i < 7; i++)
            s[i] = __builtin_amdgcn_mfma_f32_16x16x32_bf16(kf[i], qf, s[i], 0, 0, 0);
        float m = -1e30f;
#pragma unroll
        for (int i = 0; i < 7; i++)
#pragma unroll
            for (int rr = 0; rr < 4; rr++) m = fmaxf(m, s[i][rr]);
        m = fmaxf(m, __shfl_xor(m, 16));
        m = fmaxf(m, __shfl_xor(m, 32));
        float l = 0.f;
#pragma unroll
        for (int i = 0; i < 7; i++)
#pragma unroll
            for (int rr = 0; rr < 4; rr++) { s[i][rr] = __expf(s[i][rr] - m); l += s[i][rr]; }
        l += __shfl_xor(l, 16);
        l += __shfl_xor(l, 32);
#pragma unroll
        for (int i = 0; i < 7; i++) {
            u32 lo, hi;
            asm("v_cvt_pk_bf16_f32 %0, %1, %2" : "=v"(lo) : "v"(s[i][0]), "v"(s[i][1]));
            asm("v_cvt_pk_bf16_f32 %0, %1, %2" : "=v"(hi) : "v"(s[i][2]), "v"(s[i][3]));
            uint2 w; w.x = lo; w.y = hi;
            *(uint2*)(Pl + l15 * 128 + ((i * 16 + quad * 4) ^ ((l15 & 7) << 3))) = w;
        }
        f32x4 o0 = (f32x4){0.f, 0.f, 0.f, 0.f};
        f32x4 o1 = (f32x4){0.f, 0.f, 0.f, 0.f};
#pragma unroll
        for (int ks = 0; ks < 4; ks++) {
            bf16x8 pf = *(const bf16x8*)(Pl + l15 * 128 + ((ks * 32 + quad * 8) ^ ((l15 & 7) << 3)));
            o0 = __builtin_amdgcn_mfma_f32_16x16x32_bf16(vf[0][ks], pf, o0, 0, 0, 0);
            o1 = __builtin_amdgcn_mfma_f32_16x16x32_bf16(vf[1][ks], pf, o1, 0, 0, 0);
        }
        float inv = 1.0f / l;
        if (q < 100) {
            u16* cp = ctx + base + (size_t)q * 512;
            {
                float a0 = o0[0]*inv, a1 = o0[1]*inv, a2 = o0[2]*inv, a3 = o0[3]*inv;
                u32 lo, hi;
                asm("v_cvt_pk_bf16_f32 %0, %1, %2" : "=v"(lo) : "v"(a0), "v"(a1));
                asm("v_cvt_pk_bf16_f32 %0, %1, %2" : "=v"(hi) : "v"(a2), "v"(a3));
                uint2 w; w.x = lo; w.y = hi;
                *(uint2*)(cp + quad * 4) = w;
            }
            {
                float a0 = o1[0]*inv, a1 = o1[1]*inv, a2 = o1[2]*inv, a3 = o1[3]*inv;
                u32 lo, hi;
                asm("v_cvt_pk_bf16_f32 %0, %1, %2" : "=v"(lo) : "v"(a0), "v"(a1));
                asm("v_cvt_pk_bf16_f32 %0, %1, %2" : "=v"(hi) : "v"(a2), "v"(a3));
                uint2 w; w.x = lo; w.y = hi;
                *(uint2*)(cp + 16 + quad * 4) = w;
            }
        }
    }
}

extern "C" void kernel_launch(void* const* d_in, const int* in_sizes, int n_in,
                              void* d_out, int out_size, void* d_ws, size_t ws_size,
                              hipStream_t stream) {
    const float* hidden = (const float*)d_in[0];
    const float* ln1_g  = (const float*)d_in[1];
    const float* ln1_b  = (const float*)d_in[2];
    const float* wq = (const float*)d_in[3];  const float* bq = (const float*)d_in[4];
    const float* wk = (const float*)d_in[5];  const float* bk = (const float*)d_in[6];
    const float* wv = (const float*)d_in[7];  const float* bv = (const float*)d_in[8];
    const float* wo = (const float*)d_in[9];  const float* bo = (const float*)d_in[10];
    const float* rel = (const float*)d_in[11];
    const float* ln2_g = (const float*)d_in[12];
    const float* ln2_b = (const float*)d_in[13];
    const float* w1 = (const float*)d_in[14]; const float* b1 = (const float*)d_in[15];
    const float* w2 = (const float*)d_in[16]; const float* b2 = (const float*)d_in[17];

    // ws: R0,R1,Rh = 3*NTC bf16 (118MB) + weights (+6KB qkv bias). d_out doubles as V / ln2y park.
    //   R0: win -> ctx -> h1 chunk (with R1) ; R1: q -> attn_out ; Rh: k -> hs
    //   d_out lo (bf16): v -> ln2y ; biasM parked at d_out+NTC u16.
    const size_t NTC = 38400ull * 512;
    u16* ws = (u16*)d_ws;
    u16* R0 = ws;
    u16* R1 = ws + NTC;
    u16* Rh = ws + 2 * NTC;
    u16* wqt = ws + 3 * NTC;
    u16* wkt = wqt + 512 * 512;
    u16* wvt = wkt + 512 * 512;       // wqt..wvt contiguous => fused QKV Bt (1536 x 512)
    u16* wot = wvt + 512 * 512;
    u16* w1t = wot + 512 * 512;       // (2048,512)
    u16* w2t = w1t + 1048576;         // (512,2048)
    float* qkvb = (float*)(w2t + 1048576);   // concat bias [1536]
    u16* dlo = (u16*)d_out;           // v, then ln2y (bf16)
    u16* biasM = dlo + NTC;           // [4][16][100][112] bf16
    float* outp = (float*)d_out;

    const float SC = 0.17677669529663689f;   // 1/sqrt(32), folded into wq/bq

    transpose_k<<<dim3(16, 16), 256, 0, stream>>>(wq, wqt, 512, 512, SC);
    transpose_k<<<dim3(16, 16), 256, 0, stream>>>(wk, wkt, 512, 512, 1.0f);
    transpose_k<<<dim3(16, 16), 256, 0, stream>>>(wv, wvt, 512, 512, 1.0f);
    transpose_k<<<dim3(16, 16), 256, 0, stream>>>(wo, wot, 512, 512, 1.0f);
    transpose_k<<<dim3(16, 64), 256, 0, stream>>>(w1, w1t, 512, 2048, 1.0f);
    transpose_k<<<dim3(64, 16), 256, 0, stream>>>(w2, w2t, 2048, 512, 1.0f);
    biascat_k<<<6, 256, 0, stream>>>(bq, bk, bv, qkvb);
    biasprep_k<<<2800, 256, 0, stream>>>(rel, biasM);   // 716800 = 2800*256

    ln1win_k<<<9600, 256, 0, stream>>>(hidden, ln1_g, ln1_b, R0 /*win*/);

    // fused QKV (256^2, 900 blocks): cols 0..1535 over contiguous wqt|wkt|wvt -> R1 / Rh / dlo
    gemm256_k<0, 0, 1><<<dim3(150, 6), 512, 0, stream>>>(R0, wqt, qkvb, nullptr,
                                                         R1 /*q*/, Rh /*k*/, dlo /*v*/, 38400, 512, 512);

    attn_mfma_k<<<1536, 256, 0, stream>>>(R1, Rh, dlo, biasM, R0 /*ctx*/);

    // wo (N=512 -> 128^2 BK=64, 1200 blocks, 2 blocks/CU)
    gemmB_k<0, 0><<<dim3(300, 4), 256, 0, stream>>>(R0, wot, bo, nullptr,
                                                    R1 /*attn_out*/, 38400, 512, 512);

    resid2_k<<<9600, 256, 0, stream>>>(hidden, R1, ln2_g, ln2_b, Rh /*hs*/, dlo /*ln2y*/);

    // FFN in 2 chunks of 19200 rows, REVERSE order so fp32 out writes never clobber unread bf16 ln2y:
    // chunk mc reads bf16 [mc*19.66MB, +19.66MB); writes fp32 [mc*39.32MB, +39.32MB).
    for (int mc = 1; mc >= 0; mc--) {
        size_t roff = (size_t)mc * 19200 * 512;
        // h1 (N=2048 -> 256^2, 600 blocks)
        gemm256_k<1, 0, 0><<<dim3(75, 8), 512, 0, stream>>>(dlo + roff, w1t, b1, nullptr,
                                                            R0 /*h1*/, nullptr, nullptr, 19200, 2048, 512);
        // out (N=512 -> 128^2 BK=64, 600 blocks, K=2048 deep pipeline)
        gemmB_k<2, 1><<<dim3(150, 4), 256, 0, stream>>>(R0, w2t, b2, Rh + roff,
                                                        outp + roff, 19200, 512, 2048);
    }
}